// Round 7
// baseline (414.349 us; speedup 1.0000x reference)
//
#include <hip/hip_runtime.h>
#include <cstdint>

typedef unsigned long long u64;
typedef unsigned int u32;

#define NB 4096
#define NW 64            // 64-bit words per mask row
#define MM 20
#define HH 16
#define COND_THRES 0.2f
#define IOU_THRES 0.3f
#define PI_F  3.14159265358979323846f
#define PI4_F 0.78539816339744830962f

// ---- workspace layout (bytes) ----
#define WS_KEPT    0                           // u64[64] kept bitmask
#define WS_MASK    32768                       // u64[NB*NW] = 2 MiB
#define WS_BOX9S   (WS_MASK + NB*NW*8)         // float[NB*9]
#define WS_BEVS    (WS_BOX9S + NB*9*4)         // float4[NB]
#define WS_SCORES  (WS_BEVS + NB*16)           // float[NB]
#define WS_LABELS  (WS_SCORES + NB*4)          // int[NB]
#define WS_SUPSTEP (WS_LABELS + NB*4)          // int[NB]

// ---------- K1: fused key-build + single-block bitonic sort + gather + BEV.
// Ascending sort on (~score_bits << 12) | idx reproduces
// jnp.argsort(-where(valid,score,-inf)) stable semantics.
__global__ void __launch_bounds__(1024) k_sortg(const float* __restrict__ scores,
                                                const float* __restrict__ boxes9,
                                                const int* __restrict__ labels,
                                                float* __restrict__ box9s, float4* __restrict__ bevs,
                                                float* __restrict__ scoress, int* __restrict__ labelss) {
  #pragma clang fp contract(off)
  __shared__ u64 k[NB];
  for (int t = threadIdx.x; t < NB; t += 1024) {
    float s = scores[t];
    u32 sb = (s > COND_THRES) ? __float_as_uint(s) : 0u;
    k[t] = ((u64)(sb ^ 0xFFFFFFFFu) << 12) | (u64)t;
  }
  __syncthreads();
  for (int len = 2; len <= NB; len <<= 1) {
    for (int s = len >> 1; s > 0; s >>= 1) {
      for (int idx = threadIdx.x; idx < NB; idx += 1024) {
        int j = idx ^ s;
        if (j > idx) {
          bool up = ((idx & len) == 0);
          u64 a = k[idx], b = k[j];
          if ((a > b) == up) { k[idx] = b; k[j] = a; }
        }
      }
      __syncthreads();
    }
  }
  for (int r = threadIdx.x; r < NB; r += 1024) {
    int idx = (int)(k[r] & 0xFFFu);
    float b[9];
    #pragma unroll
    for (int f = 0; f < 9; ++f) b[f] = boxes9[idx * 9 + f];
    #pragma unroll
    for (int f = 0; f < 9; ++f) box9s[r * 9 + f] = b[f];
    float ang = b[6] - floorf(b[6] / PI_F + 0.5f) * PI_F;
    bool sw = fabsf(ang) >= PI4_F;
    float dx = sw ? b[4] : b[3];
    float dy = sw ? b[3] : b[4];
    bevs[r] = make_float4(b[0] - dx * 0.5f, b[1] - dy * 0.5f,
                          b[0] + dx * 0.5f, b[1] + dy * 0.5f);
    scoress[r] = scores[idx];
    labelss[r] = labels[idx];
  }
}

// ---------- K2: pairwise over-matrix (symmetric), bit-packed rows.
__global__ void __launch_bounds__(64) k_mask(const float4* __restrict__ bevs,
                                             const int* __restrict__ labelss,
                                             u64* __restrict__ mask) {
  #pragma clang fp contract(off)
  __shared__ float4 bj[64];
  __shared__ int lj[64];
  int t = threadIdx.x;
  int jt = blockIdx.x;
  int it = blockIdx.y;
  bj[t] = bevs[jt * 64 + t];
  lj[t] = labelss[jt * 64 + t];
  int i = it * 64 + t;
  float4 a = bevs[i];
  int la = labelss[i];
  float area_a = (a.z - a.x) * (a.w - a.y);
  __syncthreads();
  u64 w = 0;
  #pragma unroll 8
  for (int kk = 0; kk < 64; ++kk) {
    float4 bb = bj[kk];
    float xmin = fmaxf(a.x, bb.x), ymin = fmaxf(a.y, bb.y);
    float xmax = fminf(a.z, bb.z), ymax = fminf(a.w, bb.w);
    float inter = fmaxf(xmax - xmin, 0.0f) * fmaxf(ymax - ymin, 0.0f);
    float area_b = (bb.z - bb.x) * (bb.w - bb.y);
    float iou = inter / fmaxf(area_a + area_b - inter, 1e-6f);
    if ((iou > IOU_THRES) && (la == lj[kk])) w |= (1ull << kk);
  }
  mask[(u64)i * NW + jt] = w;
}

// ---------- K3: kept-mask, group-pipelined.
// 64 steps; step g: wave 0 resolves group g intra (ballot-skip loop over kept
// boxes only); waves 1-15 OR the kept rows of group g-1 into the external
// suppression bitmap extw[] (symmetric matrix: row_b bit j <=> b suppresses j)
// and prefetch group g's rows one step ahead. Resolver covers K[g-1]'s effect
// on its own group inline (prevcol word), so the concurrent extw[g] update by
// updaters is duplicated work, making the race benign.
__global__ void __launch_bounds__(1024) k_nms(const u64* __restrict__ mask,
                                              const float* __restrict__ scoress,
                                              u64* __restrict__ keptOut) {
  __shared__ u64 extw[64];   // external suppression bits (init: invalid)
  __shared__ u64 Kw[64];     // kept words, published per step
  int tid = threadIdx.x;
  int lane = tid & 63;
  int wave = tid >> 6;
  // init extw via per-span ballots (each wave handles 4 spans of 64 scores)
  #pragma unroll
  for (int p = 0; p < 4; ++p) {
    int s = wave + (p << 4);
    u64 bb = __ballot(!(scoress[(s << 6) | lane] > COND_THRES));
    if (lane == 0) extw[s] = bb;
  }
  // resolver prefetch (before barrier; independent of extw)
  u64 d_cur = 0, p_cur = 0, d_n1 = 0, p_n1 = 0;
  u64 B[5], C[5];
  if (wave == 0) {
    d_cur = mask[(u64)lane * 64 + 0];                 // diag(0)
    d_n1  = mask[(u64)(64 + lane) * 64 + 1];          // diag(1)
    p_n1  = mask[(u64)(64 + lane) * 64 + 0];          // prev(1)
  }
  __syncthreads();
  u64 Kg_prev = 0;
  for (int g = 0; g < 64; ++g) {
    if (wave == 0) {
      u64 d_n2 = 0, p_n2 = 0;
      if (g + 2 < 64) {
        d_n2 = mask[(u64)(((g + 2) << 6) + lane) * 64 + (g + 2)];
        p_n2 = mask[(u64)(((g + 2) << 6) + lane) * 64 + (g + 1)];
      }
      u64 ew = extw[g];
      bool supp = (((ew >> lane) & 1ull) != 0ull);
      if (g > 0) supp = supp || ((p_cur & Kg_prev) != 0ull);
      u64 rem = ~__ballot(supp);
      u64 Kg = 0;
      while (rem) {
        int b = __builtin_ctzll(rem);
        Kg |= (1ull << b);
        supp = supp || ((lane > b) && (((d_cur >> b) & 1ull) != 0ull));
        u64 bm = __ballot(supp);
        rem &= ~(bm | (1ull << b));
      }
      if (lane == 0) Kw[g] = Kg;
      Kg_prev = Kg;
      d_cur = d_n1; p_cur = p_n1; d_n1 = d_n2; p_n1 = p_n2;
    } else {
      // issue prefetch of group g rows (used at step g+1)
      if (g < 63) {
        #pragma unroll
        for (int p = 0; p < 5; ++p) {
          int r = (wave - 1) + 15 * p;
          if (r < 64) C[p] = mask[(u64)((g << 6) + r) * 64 + lane];
        }
      }
      // process kept rows of group g-1 (loaded last step into B)
      if (g >= 1) {
        u64 Kp = Kw[g - 1];
        #pragma unroll
        for (int p = 0; p < 5; ++p) {
          int r = (wave - 1) + 15 * p;
          if (r < 64 && ((Kp >> r) & 1ull)) atomicOr(&extw[lane], B[p]);
        }
      }
      #pragma unroll
      for (int p = 0; p < 5; ++p) B[p] = C[p];
    }
    __syncthreads();
  }
  if (tid < 64) keptOut[tid] = Kw[tid];
}

// ---------- K4: supstep[j] = min{i kept : over(i,j)} (parallel), -1 if invalid.
__global__ void __launch_bounds__(256) k_supstep(const u64* __restrict__ mask,
                                                 const u64* __restrict__ kept,
                                                 const float* __restrict__ scoress,
                                                 int* __restrict__ supstep) {
  __shared__ u64 K[64];
  if (threadIdx.x < 64) K[threadIdx.x] = kept[threadIdx.x];
  __syncthreads();
  int j = blockIdx.x * 256 + threadIdx.x;
  if (!(scoress[j] > COND_THRES)) { supstep[j] = -1; return; }
  int res = 0x7FFFFFFF;
  #pragma unroll 4
  for (int w = 0; w < 64; ++w) {
    u64 m = mask[(u64)j * NW + w] & K[w];
    if (m) { res = (w << 6) + __builtin_ctzll(m); break; }
  }
  supstep[j] = res;
}

// ---------- K5: per-box merge + all outputs. One 64-thread block per sorted box.
__global__ void __launch_bounds__(64) k_merge(
    const u64* __restrict__ mask, const int* __restrict__ supstep,
    const float* __restrict__ box9s, const float* __restrict__ scoress,
    const int* __restrict__ labelss,
    const float* __restrict__ w1, const float* __restrict__ b1,
    const float* __restrict__ w2, const float* __restrict__ b2,
    const float* __restrict__ w3, const float* __restrict__ b3,
    float* __restrict__ out) {
  #pragma clang fp contract(off)
  __shared__ int candList[MM];
  __shared__ float ob[MM][7];
  __shared__ float h1[7][HH];
  __shared__ float h2[7][HH];
  __shared__ float res[7];
  int i = blockIdx.x;
  int t = threadIdx.x;
  bool active = (supstep[i] == i);
  u64 wq = 0;
  int cnt = 0;
  if (active) {
    u64 w = mask[(u64)i * NW + t];
    while (w) {
      int b = __builtin_ctzll(w);
      w &= w - 1;
      int j = (t << 6) | b;
      if (supstep[j] >= i) { wq |= (1ull << b); cnt++; }
    }
  }
  int incl = cnt;
  #pragma unroll
  for (int off = 1; off < 64; off <<= 1) {
    int v = __shfl_up(incl, off);
    if (t >= off) incl += v;
  }
  int excl = incl - cnt;
  int count = __shfl(incl, 63);
  bool merged = active && (count > 1);
  if (merged && wq) {
    int pos = excl;
    u64 ww = wq;
    while (ww && pos < MM) {
      int b = __builtin_ctzll(ww);
      ww &= ww - 1;
      candList[pos++] = (t << 6) | b;
    }
  }
  __syncthreads();
  if (merged) {
    int nc = count < MM ? count : MM;
    if (t < MM) {
      if (t < nc) {
        int j = candList[t];
        #pragma unroll
        for (int f = 0; f < 7; ++f) ob[t][f] = box9s[j * 9 + f];
      } else {
        #pragma unroll
        for (int f = 0; f < 7; ++f) ob[t][f] = 0.0f;
      }
    }
    __syncthreads();
    for (int o = t; o < 7 * HH; o += 64) {
      int f = o >> 4, hh = o & 15;
      float acc = b1[hh];
      #pragma unroll
      for (int m = 0; m < MM; ++m) acc += ob[m][f] * w1[m * HH + hh];
      h1[f][hh] = fmaxf(acc, 0.0f);
    }
    __syncthreads();
    for (int o = t; o < 7 * HH; o += 64) {
      int f = o >> 4, oo = o & 15;
      float acc = b2[oo];
      #pragma unroll
      for (int k = 0; k < HH; ++k) acc += h1[f][k] * w2[k * HH + oo];
      h2[f][oo] = fmaxf(acc, 0.0f);
    }
    __syncthreads();
    if (t < 7) {
      float acc = b3[0];
      #pragma unroll
      for (int k = 0; k < HH; ++k) acc += h2[t][k] * w3[k];
      if (t >= 3 && t < 6) acc = fmaxf(acc, 1e-5f);
      res[t] = acc;
    }
    __syncthreads();
  }
  if (t < 9) {
    float v = box9s[i * 9 + t];
    if (merged && t < 7) v = res[t];
    out[i * 9 + t] = v;
  }
  if (t == 0) {
    out[NB * 9 + i]          = scoress[i];
    out[NB * 9 + NB + i]     = (float)labelss[i];
    out[NB * 9 + 2 * NB + i] = active ? 1.0f : 0.0f;
  }
}

extern "C" void kernel_launch(void* const* d_in, const int* in_sizes, int n_in,
                              void* d_out, int out_size, void* d_ws, size_t ws_size,
                              hipStream_t stream) {
  const float* boxes9 = (const float*)d_in[0];
  const float* scores = (const float*)d_in[1];
  const int*   labels = (const int*)d_in[2];
  const float* w1 = (const float*)d_in[3];
  const float* b1 = (const float*)d_in[4];
  const float* w2 = (const float*)d_in[5];
  const float* b2 = (const float*)d_in[6];
  const float* w3 = (const float*)d_in[7];
  const float* b3 = (const float*)d_in[8];
  char* ws = (char*)d_ws;
  u64*    kept    = (u64*)(ws + WS_KEPT);
  u64*    mask    = (u64*)(ws + WS_MASK);
  float*  box9s   = (float*)(ws + WS_BOX9S);
  float4* bevs    = (float4*)(ws + WS_BEVS);
  float*  scoress = (float*)(ws + WS_SCORES);
  int*    labelss = (int*)(ws + WS_LABELS);
  int*    supstep = (int*)(ws + WS_SUPSTEP);
  float*  out     = (float*)d_out;

  hipLaunchKernelGGL(k_sortg,   dim3(1),        dim3(1024), 0, stream, scores, boxes9, labels,
                     box9s, bevs, scoress, labelss);
  hipLaunchKernelGGL(k_mask,    dim3(64, 64),   dim3(64),   0, stream, bevs, labelss, mask);
  hipLaunchKernelGGL(k_nms,     dim3(1),        dim3(1024), 0, stream, mask, scoress, kept);
  hipLaunchKernelGGL(k_supstep, dim3(NB / 256), dim3(256),  0, stream, mask, kept, scoress, supstep);
  hipLaunchKernelGGL(k_merge,   dim3(NB),       dim3(64),   0, stream, mask, supstep,
                     box9s, scoress, labelss, w1, b1, w2, b2, w3, b3, out);
}

// Round 8
// 369.862 us; speedup vs baseline: 1.1203x; 1.1203x over previous
//
#include <hip/hip_runtime.h>
#include <cstdint>

typedef unsigned long long u64;
typedef unsigned int u32;

#define NB 4096
#define NW 64            // 64-bit words per mask row
#define MM 20
#define HH 16
#define COND_THRES 0.2f
#define IOU_THRES 0.3f
#define PI_F  3.14159265358979323846f
#define PI4_F 0.78539816339744830962f

// ---- workspace layout (bytes) ----
#define WS_KEPT    0                           // u64[64] kept bitmask (u32[128] LE)
#define WS_DIAG    1024                        // u32[4096]: 128 groups x 32 intra words
#define WS_MASK    32768                       // u64[NB*NW] = 2 MiB
#define WS_BOX9S   (WS_MASK + NB*NW*8)         // float[NB*9]
#define WS_BEVS    (WS_BOX9S + NB*9*4)         // float4[NB]
#define WS_SCORES  (WS_BEVS + NB*16)           // float[NB]
#define WS_LABELS  (WS_SCORES + NB*4)          // int[NB]
#define WS_SUPSTEP (WS_LABELS + NB*4)          // int[NB]

// ---------- K1: fused key-build + single-block bitonic sort + gather + BEV.
__global__ void __launch_bounds__(1024) k_sortg(const float* __restrict__ scores,
                                                const float* __restrict__ boxes9,
                                                const int* __restrict__ labels,
                                                float* __restrict__ box9s, float4* __restrict__ bevs,
                                                float* __restrict__ scoress, int* __restrict__ labelss) {
  #pragma clang fp contract(off)
  __shared__ u64 k[NB];
  for (int t = threadIdx.x; t < NB; t += 1024) {
    float s = scores[t];
    u32 sb = (s > COND_THRES) ? __float_as_uint(s) : 0u;
    k[t] = ((u64)(sb ^ 0xFFFFFFFFu) << 12) | (u64)t;
  }
  __syncthreads();
  for (int len = 2; len <= NB; len <<= 1) {
    for (int s = len >> 1; s > 0; s >>= 1) {
      for (int idx = threadIdx.x; idx < NB; idx += 1024) {
        int j = idx ^ s;
        if (j > idx) {
          bool up = ((idx & len) == 0);
          u64 a = k[idx], b = k[j];
          if ((a > b) == up) { k[idx] = b; k[j] = a; }
        }
      }
      __syncthreads();
    }
  }
  for (int r = threadIdx.x; r < NB; r += 1024) {
    int idx = (int)(k[r] & 0xFFFu);
    float b[9];
    #pragma unroll
    for (int f = 0; f < 9; ++f) b[f] = boxes9[idx * 9 + f];
    #pragma unroll
    for (int f = 0; f < 9; ++f) box9s[r * 9 + f] = b[f];
    float ang = b[6] - floorf(b[6] / PI_F + 0.5f) * PI_F;
    bool sw = fabsf(ang) >= PI4_F;
    float dx = sw ? b[4] : b[3];
    float dy = sw ? b[3] : b[4];
    bevs[r] = make_float4(b[0] - dx * 0.5f, b[1] - dy * 0.5f,
                          b[0] + dx * 0.5f, b[1] + dy * 0.5f);
    scoress[r] = scores[idx];
    labelss[r] = labels[idx];
  }
}

// ---------- K2: pairwise over-matrix (symmetric), bit-packed rows + diag slices.
__global__ void __launch_bounds__(64) k_mask(const float4* __restrict__ bevs,
                                             const int* __restrict__ labelss,
                                             u64* __restrict__ mask,
                                             u32* __restrict__ diag) {
  #pragma clang fp contract(off)
  __shared__ float4 bj[64];
  __shared__ int lj[64];
  int t = threadIdx.x;
  int jt = blockIdx.x;
  int it = blockIdx.y;
  bj[t] = bevs[jt * 64 + t];
  lj[t] = labelss[jt * 64 + t];
  int i = it * 64 + t;
  float4 a = bevs[i];
  int la = labelss[i];
  float area_a = (a.z - a.x) * (a.w - a.y);
  __syncthreads();
  u64 w = 0;
  #pragma unroll 8
  for (int kk = 0; kk < 64; ++kk) {
    float4 bb = bj[kk];
    float xmin = fmaxf(a.x, bb.x), ymin = fmaxf(a.y, bb.y);
    float xmax = fminf(a.z, bb.z), ymax = fminf(a.w, bb.w);
    float inter = fmaxf(xmax - xmin, 0.0f) * fmaxf(ymax - ymin, 0.0f);
    float area_b = (bb.z - bb.x) * (bb.w - bb.y);
    float iou = inter / fmaxf(area_a + area_b - inter, 1e-6f);
    if ((iou > IOU_THRES) && (la == lj[kk])) w |= (1ull << kk);
  }
  mask[(u64)i * NW + jt] = w;
  if (it == jt) {
    // group of 32: g = 2*it + (t>=32); intra word = matching 32-bit half of w
    int g = (it << 1) | (t >> 5);
    diag[g * 32 + (t & 31)] = (t < 32) ? (u32)w : (u32)(w >> 32);
  }
}

// ---------- K3: kept-mask. Wave 0 = resolver: per 32-box group, SGPR intra
// matrix D (scalar loads) + branchless SALU recurrence; per-box path has zero
// cross-lane ops. Kept rows ORed into distributed sup from LDS. Waves 1-15
// stage 128-row chunks global->LDS double-buffered (R5 producer).
#define SC 128                   // rows per chunk (= 4 groups of 32)
#define NCH (NB / SC)            // 32
#define PW 15                    // producer waves
__device__ __forceinline__ void stage_chunk(const u64* __restrict__ mask, u64* __restrict__ dst,
                                            int chunk, int wave, int lane) {
  const ulonglong2* __restrict__ src2 = (const ulonglong2*)(mask + (u64)chunk * SC * 64);
  ulonglong2* dst2 = (ulonglong2*)dst;
  ulonglong2 tmp[5];
  #pragma unroll
  for (int p = 0; p < 5; ++p) {
    int ci = (wave - 1) + PW * p;
    if (ci < 64) tmp[p] = src2[ci * 64 + lane];   // back-to-back issue
  }
  #pragma unroll
  for (int p = 0; p < 5; ++p) {
    int ci = (wave - 1) + PW * p;
    if (ci < 64) dst2[ci * 64 + lane] = tmp[p];
  }
}
__global__ void __launch_bounds__(1024) k_nms(const u64* __restrict__ mask,
                                              const u32* __restrict__ diag,
                                              const float* __restrict__ scoress,
                                              u32* __restrict__ keptOut32) {
  __shared__ __align__(16) u64 buf[2][SC * 64];   // 128 KiB
  __shared__ u32 Kw32[128];
  int tid = threadIdx.x;
  int lane = tid & 63;
  int wave = tid >> 6;
  u64 sup = 0;
  u32 Dc[32];
  if (wave == 0) {
    // lane L owns word L of sup; init with invalid bits (batched float4 loads)
    const float4* s4 = (const float4*)scoress;
    #pragma unroll
    for (int h = 0; h < 2; ++h) {
      float4 sv[8];
      #pragma unroll
      for (int p = 0; p < 8; ++p) sv[p] = s4[lane * 16 + h * 8 + p];
      #pragma unroll
      for (int p = 0; p < 8; ++p) {
        int base = (h * 8 + p) * 4;
        if (!(sv[p].x > COND_THRES)) sup |= 1ull << base;
        if (!(sv[p].y > COND_THRES)) sup |= 1ull << (base + 1);
        if (!(sv[p].z > COND_THRES)) sup |= 1ull << (base + 2);
        if (!(sv[p].w > COND_THRES)) sup |= 1ull << (base + 3);
      }
    }
    #pragma unroll
    for (int w = 0; w < 32; ++w) Dc[w] = diag[w];   // group 0 intra matrix
  } else {
    stage_chunk(mask, buf[0], 0, wave, lane);
  }
  __syncthreads();
  for (int c = 0; c < NCH; ++c) {
    if (wave != 0) {
      if (c + 1 < NCH) stage_chunk(mask, buf[(c + 1) & 1], c + 1, wave, lane);
    } else {
      const u64* lbuf = buf[c & 1];
      #pragma unroll
      for (int gg = 0; gg < 4; ++gg) {
        const int g = c * 4 + gg;
        // prefetch next group's intra matrix (uniform -> scalar loads)
        u32 Dn[32];
        const int gn = (g + 1 < 128) ? (g + 1) : 127;
        #pragma unroll
        for (int w = 0; w < 32; ++w) Dn[w] = diag[gn * 32 + w];
        // entry suppression: 32-bit half (g&1) of sup word (g>>1)
        int src = g >> 1;
        u32 wlo = __builtin_amdgcn_readlane((u32)sup, src);
        u32 whi = __builtin_amdgcn_readlane((u32)(sup >> 32), src);
        u32 s = ((g & 1) ? whi : wlo);
        // branchless SALU greedy over 32 boxes
        u32 k32 = 0;
        #pragma unroll
        for (int b = 0; b < 32; ++b) {
          u32 bit = (s >> b) & 1u;
          u32 m = bit - 1u;              // all-ones if kept
          k32 |= (1u << b) & m;
          s |= Dc[b] & m;
        }
        if (lane == 0) Kw32[g] = k32;
        // OR kept rows into distributed sup
        u32 kk = k32;
        while (kk) {
          int b = __builtin_ctz(kk);
          kk &= kk - 1;
          sup |= lbuf[(gg * 32 + b) * 64 + lane];
        }
        #pragma unroll
        for (int w = 0; w < 32; ++w) Dc[w] = Dn[w];
      }
    }
    __syncthreads();
  }
  if (tid < 128) keptOut32[tid] = Kw32[tid];
}

// ---------- K4: supstep[j] = min{i kept : over(i,j)} (parallel), -1 if invalid.
__global__ void __launch_bounds__(256) k_supstep(const u64* __restrict__ mask,
                                                 const u64* __restrict__ kept,
                                                 const float* __restrict__ scoress,
                                                 int* __restrict__ supstep) {
  __shared__ u64 K[64];
  if (threadIdx.x < 64) K[threadIdx.x] = kept[threadIdx.x];
  __syncthreads();
  int j = blockIdx.x * 256 + threadIdx.x;
  if (!(scoress[j] > COND_THRES)) { supstep[j] = -1; return; }
  int res = 0x7FFFFFFF;
  #pragma unroll 4
  for (int w = 0; w < 64; ++w) {
    u64 m = mask[(u64)j * NW + w] & K[w];
    if (m) { res = (w << 6) + __builtin_ctzll(m); break; }
  }
  supstep[j] = res;
}

// ---------- K5: per-box merge + all outputs. One 64-thread block per sorted box.
__global__ void __launch_bounds__(64) k_merge(
    const u64* __restrict__ mask, const int* __restrict__ supstep,
    const float* __restrict__ box9s, const float* __restrict__ scoress,
    const int* __restrict__ labelss,
    const float* __restrict__ w1, const float* __restrict__ b1,
    const float* __restrict__ w2, const float* __restrict__ b2,
    const float* __restrict__ w3, const float* __restrict__ b3,
    float* __restrict__ out) {
  #pragma clang fp contract(off)
  __shared__ int candList[MM];
  __shared__ float ob[MM][7];
  __shared__ float h1[7][HH];
  __shared__ float h2[7][HH];
  __shared__ float res[7];
  int i = blockIdx.x;
  int t = threadIdx.x;
  bool active = (supstep[i] == i);
  u64 wq = 0;
  int cnt = 0;
  if (active) {
    u64 w = mask[(u64)i * NW + t];
    while (w) {
      int b = __builtin_ctzll(w);
      w &= w - 1;
      int j = (t << 6) | b;
      if (supstep[j] >= i) { wq |= (1ull << b); cnt++; }
    }
  }
  int incl = cnt;
  #pragma unroll
  for (int off = 1; off < 64; off <<= 1) {
    int v = __shfl_up(incl, off);
    if (t >= off) incl += v;
  }
  int excl = incl - cnt;
  int count = __shfl(incl, 63);
  bool merged = active && (count > 1);
  if (merged && wq) {
    int pos = excl;
    u64 ww = wq;
    while (ww && pos < MM) {
      int b = __builtin_ctzll(ww);
      ww &= ww - 1;
      candList[pos++] = (t << 6) | b;
    }
  }
  __syncthreads();
  if (merged) {
    int nc = count < MM ? count : MM;
    if (t < MM) {
      if (t < nc) {
        int j = candList[t];
        #pragma unroll
        for (int f = 0; f < 7; ++f) ob[t][f] = box9s[j * 9 + f];
      } else {
        #pragma unroll
        for (int f = 0; f < 7; ++f) ob[t][f] = 0.0f;
      }
    }
    __syncthreads();
    for (int o = t; o < 7 * HH; o += 64) {
      int f = o >> 4, hh = o & 15;
      float acc = b1[hh];
      #pragma unroll
      for (int m = 0; m < MM; ++m) acc += ob[m][f] * w1[m * HH + hh];
      h1[f][hh] = fmaxf(acc, 0.0f);
    }
    __syncthreads();
    for (int o = t; o < 7 * HH; o += 64) {
      int f = o >> 4, oo = o & 15;
      float acc = b2[oo];
      #pragma unroll
      for (int k = 0; k < HH; ++k) acc += h1[f][k] * w2[k * HH + oo];
      h2[f][oo] = fmaxf(acc, 0.0f);
    }
    __syncthreads();
    if (t < 7) {
      float acc = b3[0];
      #pragma unroll
      for (int k = 0; k < HH; ++k) acc += h2[t][k] * w3[k];
      if (t >= 3 && t < 6) acc = fmaxf(acc, 1e-5f);
      res[t] = acc;
    }
    __syncthreads();
  }
  if (t < 9) {
    float v = box9s[i * 9 + t];
    if (merged && t < 7) v = res[t];
    out[i * 9 + t] = v;
  }
  if (t == 0) {
    out[NB * 9 + i]          = scoress[i];
    out[NB * 9 + NB + i]     = (float)labelss[i];
    out[NB * 9 + 2 * NB + i] = active ? 1.0f : 0.0f;
  }
}

extern "C" void kernel_launch(void* const* d_in, const int* in_sizes, int n_in,
                              void* d_out, int out_size, void* d_ws, size_t ws_size,
                              hipStream_t stream) {
  const float* boxes9 = (const float*)d_in[0];
  const float* scores = (const float*)d_in[1];
  const int*   labels = (const int*)d_in[2];
  const float* w1 = (const float*)d_in[3];
  const float* b1 = (const float*)d_in[4];
  const float* w2 = (const float*)d_in[5];
  const float* b2 = (const float*)d_in[6];
  const float* w3 = (const float*)d_in[7];
  const float* b3 = (const float*)d_in[8];
  char* ws = (char*)d_ws;
  u64*    kept    = (u64*)(ws + WS_KEPT);
  u32*    diag    = (u32*)(ws + WS_DIAG);
  u64*    mask    = (u64*)(ws + WS_MASK);
  float*  box9s   = (float*)(ws + WS_BOX9S);
  float4* bevs    = (float4*)(ws + WS_BEVS);
  float*  scoress = (float*)(ws + WS_SCORES);
  int*    labelss = (int*)(ws + WS_LABELS);
  int*    supstep = (int*)(ws + WS_SUPSTEP);
  float*  out     = (float*)d_out;

  hipLaunchKernelGGL(k_sortg,   dim3(1),        dim3(1024), 0, stream, scores, boxes9, labels,
                     box9s, bevs, scoress, labelss);
  hipLaunchKernelGGL(k_mask,    dim3(64, 64),   dim3(64),   0, stream, bevs, labelss, mask, diag);
  hipLaunchKernelGGL(k_nms,     dim3(1),        dim3(1024), 0, stream, mask, diag, scoress, (u32*)kept);
  hipLaunchKernelGGL(k_supstep, dim3(NB / 256), dim3(256),  0, stream, mask, kept, scoress, supstep);
  hipLaunchKernelGGL(k_merge,   dim3(NB),       dim3(64),   0, stream, mask, supstep,
                     box9s, scoress, labelss, w1, b1, w2, b2, w3, b3, out);
}

// Round 9
// 201.666 us; speedup vs baseline: 2.0546x; 1.8340x over previous
//
#include <hip/hip_runtime.h>
#include <cstdint>

typedef unsigned long long u64;
typedef unsigned int u32;

#define NB 4096
#define NW 64            // 64-bit words per mask row
#define MM 20
#define HH 16
#define COND_THRES 0.2f
#define IOU_THRES 0.3f
#define PI_F  3.14159265358979323846f
#define PI4_F 0.78539816339744830962f

// ---- workspace layout (bytes) ----
#define WS_KEPT    0                           // u64[64] kept bitmask
#define WS_MASK    32768                       // u64[NB*NW] = 2 MiB
#define WS_BOX9S   (WS_MASK + NB*NW*8)         // float[NB*9]
#define WS_BEVS    (WS_BOX9S + NB*9*4)         // float4[NB]
#define WS_SCORES  (WS_BEVS + NB*16)           // float[NB]
#define WS_LABELS  (WS_SCORES + NB*4)          // int[NB]
#define WS_SUPSTEP (WS_LABELS + NB*4)          // int[NB]
#define WS_NBRW    (WS_SUPSTEP + NB*4)         // u64[NB]

// ---------- K1: fused key-build + single-block bitonic sort + gather + BEV.
__global__ void __launch_bounds__(1024) k_sortg(const float* __restrict__ scores,
                                                const float* __restrict__ boxes9,
                                                const int* __restrict__ labels,
                                                float* __restrict__ box9s, float4* __restrict__ bevs,
                                                float* __restrict__ scoress, int* __restrict__ labelss) {
  #pragma clang fp contract(off)
  __shared__ u64 k[NB];
  for (int t = threadIdx.x; t < NB; t += 1024) {
    float s = scores[t];
    u32 sb = (s > COND_THRES) ? __float_as_uint(s) : 0u;
    k[t] = ((u64)(sb ^ 0xFFFFFFFFu) << 12) | (u64)t;
  }
  __syncthreads();
  for (int len = 2; len <= NB; len <<= 1) {
    for (int s = len >> 1; s > 0; s >>= 1) {
      for (int idx = threadIdx.x; idx < NB; idx += 1024) {
        int j = idx ^ s;
        if (j > idx) {
          bool up = ((idx & len) == 0);
          u64 a = k[idx], b = k[j];
          if ((a > b) == up) { k[idx] = b; k[j] = a; }
        }
      }
      __syncthreads();
    }
  }
  for (int r = threadIdx.x; r < NB; r += 1024) {
    int idx = (int)(k[r] & 0xFFFu);
    float b[9];
    #pragma unroll
    for (int f = 0; f < 9; ++f) b[f] = boxes9[idx * 9 + f];
    #pragma unroll
    for (int f = 0; f < 9; ++f) box9s[r * 9 + f] = b[f];
    float ang = b[6] - floorf(b[6] / PI_F + 0.5f) * PI_F;
    bool sw = fabsf(ang) >= PI4_F;
    float dx = sw ? b[4] : b[3];
    float dy = sw ? b[3] : b[4];
    bevs[r] = make_float4(b[0] - dx * 0.5f, b[1] - dy * 0.5f,
                          b[0] + dx * 0.5f, b[1] + dy * 0.5f);
    scoress[r] = scores[idx];
    labelss[r] = labels[idx];
  }
}

// ---------- K2: pairwise over-matrix (symmetric), bit-packed rows.
__global__ void __launch_bounds__(64) k_mask(const float4* __restrict__ bevs,
                                             const int* __restrict__ labelss,
                                             u64* __restrict__ mask) {
  #pragma clang fp contract(off)
  __shared__ float4 bj[64];
  __shared__ int lj[64];
  int t = threadIdx.x;
  int jt = blockIdx.x;
  int it = blockIdx.y;
  bj[t] = bevs[jt * 64 + t];
  lj[t] = labelss[jt * 64 + t];
  int i = it * 64 + t;
  float4 a = bevs[i];
  int la = labelss[i];
  float area_a = (a.z - a.x) * (a.w - a.y);
  __syncthreads();
  u64 w = 0;
  #pragma unroll 8
  for (int kk = 0; kk < 64; ++kk) {
    float4 bb = bj[kk];
    float xmin = fmaxf(a.x, bb.x), ymin = fmaxf(a.y, bb.y);
    float xmax = fminf(a.z, bb.z), ymax = fminf(a.w, bb.w);
    float inter = fmaxf(xmax - xmin, 0.0f) * fmaxf(ymax - ymin, 0.0f);
    float area_b = (bb.z - bb.x) * (bb.w - bb.y);
    float iou = inter / fmaxf(area_a + area_b - inter, 1e-6f);
    if ((iou > IOU_THRES) && (la == lj[kk])) w |= (1ull << kk);
  }
  mask[(u64)i * NW + jt] = w;
}

// ---------- K2b: nbrw[i] = bitmask of row-words holding EARLIER VALID neighbors.
__global__ void __launch_bounds__(256) k_nbrw(const u64* __restrict__ mask,
                                              const float* __restrict__ scoress,
                                              u64* __restrict__ nbrw) {
  __shared__ u64 validw[64];
  int tid = threadIdx.x;
  if (tid < 64) {
    u64 v = 0;
    #pragma unroll 8
    for (int b = 0; b < 64; ++b)
      if (scoress[(tid << 6) | b] > COND_THRES) v |= (1ull << b);
    validw[tid] = v;
  }
  __syncthreads();
  int i = blockIdx.x * 256 + tid;
  int wi = i >> 6, bi = i & 63;
  u64 nw = 0;
  for (int w = 0; w <= wi; ++w) {
    u64 below = (w < wi) ? ~0ull : ((bi == 0) ? 0ull : ((1ull << bi) - 1ull));
    if (mask[(u64)i * NW + w] & validw[w] & below) nw |= (1ull << w);
  }
  nbrw[i] = nw;
}

// ---------- K3: greedy NMS as a parallel dependency-respecting fixpoint.
// Box i decidable when all earlier valid neighbors decided; kept iff no kept
// earlier neighbor. Jacobi rounds (decisions applied after a barrier) — exact
// equivalence to the sequential scan (confluent fixpoint; min undecided box
// always decides => guaranteed progress). Graph is sub-percolation => few rounds.
__global__ void __launch_bounds__(1024) k_nms(const u64* __restrict__ mask,
                                              const u64* __restrict__ nbrw,
                                              const float* __restrict__ scoress,
                                              u64* __restrict__ keptOut) {
  __shared__ u64 decided[64], kept[64];
  __shared__ int remaining;
  int tid = threadIdx.x;
  if (tid < 64) {
    u64 v = 0;
    #pragma unroll 8
    for (int b = 0; b < 64; ++b)
      if (scoress[(tid << 6) | b] > COND_THRES) v |= (1ull << b);
    decided[tid] = ~v;       // invalid boxes decided (kept=0) from the start
    kept[tid] = 0;
  }
  if (tid == 0) remaining = 0;
  __syncthreads();
  if (tid < 64) atomicAdd(&remaining, __popcll(~decided[tid]));
  u64 mynbrw[4];
  #pragma unroll
  for (int s = 0; s < 4; ++s) mynbrw[s] = nbrw[tid + (s << 10)];
  __syncthreads();
  while (remaining > 0) {
    int decIdx[4]; bool decKept[4]; int nDec = 0;
    #pragma unroll
    for (int s = 0; s < 4; ++s) {
      int i = tid + (s << 10);
      int wi = i >> 6;
      u64 bit = 1ull << (i & 63);
      if (!(decided[wi] & bit)) {
        bool hasU = false, hasK = false;
        u64 t = mynbrw[s];
        while (t) {
          int w = __builtin_ctzll(t);
          t &= t - 1;
          u64 below = (w < wi) ? ~0ull : (bit - 1ull);
          u64 m = mask[(u64)i * NW + w] & below;
          u64 d = decided[w];
          u64 kp = kept[w];
          hasU = hasU || ((m & ~d) != 0ull);
          hasK = hasK || ((m & kp) != 0ull);
        }
        if (!hasU) { decIdx[nDec] = i; decKept[nDec] = !hasK; ++nDec; }
      }
    }
    __syncthreads();
    for (int d = 0; d < nDec; ++d) {
      int i = decIdx[d];
      u64 bit = 1ull << (i & 63);
      atomicOr(&decided[i >> 6], bit);
      if (decKept[d]) atomicOr(&kept[i >> 6], bit);
      atomicSub(&remaining, 1);
    }
    __syncthreads();
  }
  if (tid < 64) keptOut[tid] = kept[tid];
}

// ---------- K4: supstep[j] = min{i kept : over(i,j)} (parallel), -1 if invalid.
__global__ void __launch_bounds__(256) k_supstep(const u64* __restrict__ mask,
                                                 const u64* __restrict__ kept,
                                                 const float* __restrict__ scoress,
                                                 int* __restrict__ supstep) {
  __shared__ u64 K[64];
  if (threadIdx.x < 64) K[threadIdx.x] = kept[threadIdx.x];
  __syncthreads();
  int j = blockIdx.x * 256 + threadIdx.x;
  if (!(scoress[j] > COND_THRES)) { supstep[j] = -1; return; }
  int res = 0x7FFFFFFF;
  #pragma unroll 4
  for (int w = 0; w < 64; ++w) {
    u64 m = mask[(u64)j * NW + w] & K[w];
    if (m) { res = (w << 6) + __builtin_ctzll(m); break; }
  }
  supstep[j] = res;
}

// ---------- K5: per-box merge + all outputs. One 64-thread block per sorted box.
__global__ void __launch_bounds__(64) k_merge(
    const u64* __restrict__ mask, const int* __restrict__ supstep,
    const float* __restrict__ box9s, const float* __restrict__ scoress,
    const int* __restrict__ labelss,
    const float* __restrict__ w1, const float* __restrict__ b1,
    const float* __restrict__ w2, const float* __restrict__ b2,
    const float* __restrict__ w3, const float* __restrict__ b3,
    float* __restrict__ out) {
  #pragma clang fp contract(off)
  __shared__ int candList[MM];
  __shared__ float ob[MM][7];
  __shared__ float h1[7][HH];
  __shared__ float h2[7][HH];
  __shared__ float res[7];
  int i = blockIdx.x;
  int t = threadIdx.x;
  bool active = (supstep[i] == i);
  u64 wq = 0;
  int cnt = 0;
  if (active) {
    u64 w = mask[(u64)i * NW + t];
    while (w) {
      int b = __builtin_ctzll(w);
      w &= w - 1;
      int j = (t << 6) | b;
      if (supstep[j] >= i) { wq |= (1ull << b); cnt++; }
    }
  }
  int incl = cnt;
  #pragma unroll
  for (int off = 1; off < 64; off <<= 1) {
    int v = __shfl_up(incl, off);
    if (t >= off) incl += v;
  }
  int excl = incl - cnt;
  int count = __shfl(incl, 63);
  bool merged = active && (count > 1);
  if (merged && wq) {
    int pos = excl;
    u64 ww = wq;
    while (ww && pos < MM) {
      int b = __builtin_ctzll(ww);
      ww &= ww - 1;
      candList[pos++] = (t << 6) | b;
    }
  }
  __syncthreads();
  if (merged) {
    int nc = count < MM ? count : MM;
    if (t < MM) {
      if (t < nc) {
        int j = candList[t];
        #pragma unroll
        for (int f = 0; f < 7; ++f) ob[t][f] = box9s[j * 9 + f];
      } else {
        #pragma unroll
        for (int f = 0; f < 7; ++f) ob[t][f] = 0.0f;
      }
    }
    __syncthreads();
    for (int o = t; o < 7 * HH; o += 64) {
      int f = o >> 4, hh = o & 15;
      float acc = b1[hh];
      #pragma unroll
      for (int m = 0; m < MM; ++m) acc += ob[m][f] * w1[m * HH + hh];
      h1[f][hh] = fmaxf(acc, 0.0f);
    }
    __syncthreads();
    for (int o = t; o < 7 * HH; o += 64) {
      int f = o >> 4, oo = o & 15;
      float acc = b2[oo];
      #pragma unroll
      for (int k = 0; k < HH; ++k) acc += h1[f][k] * w2[k * HH + oo];
      h2[f][oo] = fmaxf(acc, 0.0f);
    }
    __syncthreads();
    if (t < 7) {
      float acc = b3[0];
      #pragma unroll
      for (int k = 0; k < HH; ++k) acc += h2[t][k] * w3[k];
      if (t >= 3 && t < 6) acc = fmaxf(acc, 1e-5f);
      res[t] = acc;
    }
    __syncthreads();
  }
  if (t < 9) {
    float v = box9s[i * 9 + t];
    if (merged && t < 7) v = res[t];
    out[i * 9 + t] = v;
  }
  if (t == 0) {
    out[NB * 9 + i]          = scoress[i];
    out[NB * 9 + NB + i]     = (float)labelss[i];
    out[NB * 9 + 2 * NB + i] = active ? 1.0f : 0.0f;
  }
}

extern "C" void kernel_launch(void* const* d_in, const int* in_sizes, int n_in,
                              void* d_out, int out_size, void* d_ws, size_t ws_size,
                              hipStream_t stream) {
  const float* boxes9 = (const float*)d_in[0];
  const float* scores = (const float*)d_in[1];
  const int*   labels = (const int*)d_in[2];
  const float* w1 = (const float*)d_in[3];
  const float* b1 = (const float*)d_in[4];
  const float* w2 = (const float*)d_in[5];
  const float* b2 = (const float*)d_in[6];
  const float* w3 = (const float*)d_in[7];
  const float* b3 = (const float*)d_in[8];
  char* ws = (char*)d_ws;
  u64*    kept    = (u64*)(ws + WS_KEPT);
  u64*    mask    = (u64*)(ws + WS_MASK);
  float*  box9s   = (float*)(ws + WS_BOX9S);
  float4* bevs    = (float4*)(ws + WS_BEVS);
  float*  scoress = (float*)(ws + WS_SCORES);
  int*    labelss = (int*)(ws + WS_LABELS);
  int*    supstep = (int*)(ws + WS_SUPSTEP);
  u64*    nbrw    = (u64*)(ws + WS_NBRW);
  float*  out     = (float*)d_out;

  hipLaunchKernelGGL(k_sortg,   dim3(1),        dim3(1024), 0, stream, scores, boxes9, labels,
                     box9s, bevs, scoress, labelss);
  hipLaunchKernelGGL(k_mask,    dim3(64, 64),   dim3(64),   0, stream, bevs, labelss, mask);
  hipLaunchKernelGGL(k_nbrw,    dim3(NB / 256), dim3(256),  0, stream, mask, scoress, nbrw);
  hipLaunchKernelGGL(k_nms,     dim3(1),        dim3(1024), 0, stream, mask, nbrw, scoress, kept);
  hipLaunchKernelGGL(k_supstep, dim3(NB / 256), dim3(256),  0, stream, mask, kept, scoress, supstep);
  hipLaunchKernelGGL(k_merge,   dim3(NB),       dim3(64),   0, stream, mask, supstep,
                     box9s, scoress, labelss, w1, b1, w2, b2, w3, b3, out);
}

// Round 10
// 144.159 us; speedup vs baseline: 2.8743x; 1.3989x over previous
//
#include <hip/hip_runtime.h>
#include <cstdint>

typedef unsigned long long u64;
typedef unsigned int u32;

#define NB 4096
#define NW 64            // 64-bit words per mask row
#define MM 20
#define HH 16
#define COND_THRES 0.2f
#define IOU_THRES 0.3f
#define PI_F  3.14159265358979323846f
#define PI4_F 0.78539816339744830962f

// ---- workspace layout (bytes) ----
#define WS_KEPT    0                           // u64[64] kept bitmask
#define WS_MASK    32768                       // u64[NB*NW] = 2 MiB
#define WS_BOX9S   (WS_MASK + NB*NW*8)         // float[NB*9]
#define WS_BEVS    (WS_BOX9S + NB*9*4)         // float4[NB]
#define WS_SCORES  (WS_BEVS + NB*16)           // float[NB]
#define WS_LABELS  (WS_SCORES + NB*4)          // int[NB]
#define WS_SUPSTEP (WS_LABELS + NB*4)          // int[NB]
#define WS_NBRW    (WS_SUPSTEP + NB*4)         // u64[NB]
#define WS_RANK    (WS_NBRW + NB*8)            // u32[NB]

__device__ __forceinline__ u64 sort_key(float s, int i) {
  u32 sb = (s > COND_THRES) ? __float_as_uint(s) : 0u;
  return ((u64)(sb ^ 0xFFFFFFFFu) << 12) | (u64)i;
}

// ---------- K1a: counting-rank. rank[i] = #{j : key_j < key_i} (keys unique).
// Ascending rank on (~score_bits<<12)|idx == jnp.argsort(-where(valid,s,-inf))
// stable semantics (desc score, ties by idx, invalid last in idx order).
#define RJT 512
__global__ void __launch_bounds__(256) k_rank(const float* __restrict__ scores,
                                              u32* __restrict__ rank) {
  __shared__ u64 kj[RJT];
  int tid = threadIdx.x;
  int jbase = blockIdx.y * RJT;
  for (int t = tid; t < RJT; t += 256) {
    int j = jbase + t;
    kj[t] = sort_key(scores[j], j);
  }
  __syncthreads();
  int i = blockIdx.x * 256 + tid;
  u64 ki = sort_key(scores[i], i);
  int cnt = 0;
  #pragma unroll 8
  for (int t = 0; t < RJT; ++t) cnt += (kj[t] < ki) ? 1 : 0;   // LDS broadcast reads
  atomicAdd(&rank[i], (u32)cnt);
}

// ---------- K1b: scatter gather + BEV into sorted order.
__global__ void __launch_bounds__(256) k_scatter(const u32* __restrict__ rank,
                                                 const float* __restrict__ scores,
                                                 const float* __restrict__ boxes9,
                                                 const int* __restrict__ labels,
                                                 float* __restrict__ box9s, float4* __restrict__ bevs,
                                                 float* __restrict__ scoress, int* __restrict__ labelss) {
  #pragma clang fp contract(off)
  int i = blockIdx.x * 256 + threadIdx.x;
  int r = (int)rank[i];
  float b[9];
  #pragma unroll
  for (int f = 0; f < 9; ++f) b[f] = boxes9[i * 9 + f];
  #pragma unroll
  for (int f = 0; f < 9; ++f) box9s[r * 9 + f] = b[f];
  float ang = b[6] - floorf(b[6] / PI_F + 0.5f) * PI_F;
  bool sw = fabsf(ang) >= PI4_F;
  float dx = sw ? b[4] : b[3];
  float dy = sw ? b[3] : b[4];
  bevs[r] = make_float4(b[0] - dx * 0.5f, b[1] - dy * 0.5f,
                        b[0] + dx * 0.5f, b[1] + dy * 0.5f);
  scoress[r] = scores[i];
  labelss[r] = labels[i];
}

// ---------- K2: pairwise over-matrix (symmetric), bit-packed rows.
__global__ void __launch_bounds__(64) k_mask(const float4* __restrict__ bevs,
                                             const int* __restrict__ labelss,
                                             u64* __restrict__ mask) {
  #pragma clang fp contract(off)
  __shared__ float4 bj[64];
  __shared__ int lj[64];
  int t = threadIdx.x;
  int jt = blockIdx.x;
  int it = blockIdx.y;
  bj[t] = bevs[jt * 64 + t];
  lj[t] = labelss[jt * 64 + t];
  int i = it * 64 + t;
  float4 a = bevs[i];
  int la = labelss[i];
  float area_a = (a.z - a.x) * (a.w - a.y);
  __syncthreads();
  u64 w = 0;
  #pragma unroll 8
  for (int kk = 0; kk < 64; ++kk) {
    float4 bb = bj[kk];
    float xmin = fmaxf(a.x, bb.x), ymin = fmaxf(a.y, bb.y);
    float xmax = fminf(a.z, bb.z), ymax = fminf(a.w, bb.w);
    float inter = fmaxf(xmax - xmin, 0.0f) * fmaxf(ymax - ymin, 0.0f);
    float area_b = (bb.z - bb.x) * (bb.w - bb.y);
    float iou = inter / fmaxf(area_a + area_b - inter, 1e-6f);
    if ((iou > IOU_THRES) && (la == lj[kk])) w |= (1ull << kk);
  }
  mask[(u64)i * NW + jt] = w;
}

// ---------- K2b: nbrw[i] = bitmask of row-words holding EARLIER VALID neighbors.
__global__ void __launch_bounds__(256) k_nbrw(const u64* __restrict__ mask,
                                              const float* __restrict__ scoress,
                                              u64* __restrict__ nbrw) {
  __shared__ u64 validw[64];
  int tid = threadIdx.x;
  if (tid < 64) {
    u64 v = 0;
    #pragma unroll 8
    for (int b = 0; b < 64; ++b)
      if (scoress[(tid << 6) | b] > COND_THRES) v |= (1ull << b);
    validw[tid] = v;
  }
  __syncthreads();
  int i = blockIdx.x * 256 + tid;
  int wi = i >> 6, bi = i & 63;
  u64 nw = 0;
  for (int w = 0; w <= wi; ++w) {
    u64 below = (w < wi) ? ~0ull : ((bi == 0) ? 0ull : ((1ull << bi) - 1ull));
    if (mask[(u64)i * NW + w] & validw[w] & below) nw |= (1ull << w);
  }
  nbrw[i] = nw;
}

// ---------- K3: greedy NMS as a parallel dependency-respecting fixpoint.
__global__ void __launch_bounds__(1024) k_nms(const u64* __restrict__ mask,
                                              const u64* __restrict__ nbrw,
                                              const float* __restrict__ scoress,
                                              u64* __restrict__ keptOut) {
  __shared__ u64 decided[64], kept[64];
  __shared__ int remaining;
  int tid = threadIdx.x;
  if (tid < 64) {
    u64 v = 0;
    #pragma unroll 8
    for (int b = 0; b < 64; ++b)
      if (scoress[(tid << 6) | b] > COND_THRES) v |= (1ull << b);
    decided[tid] = ~v;       // invalid boxes decided (kept=0) from the start
    kept[tid] = 0;
  }
  if (tid == 0) remaining = 0;
  __syncthreads();
  if (tid < 64) atomicAdd(&remaining, __popcll(~decided[tid]));
  u64 mynbrw[4];
  #pragma unroll
  for (int s = 0; s < 4; ++s) mynbrw[s] = nbrw[tid + (s << 10)];
  __syncthreads();
  while (remaining > 0) {
    int decIdx[4]; bool decKept[4]; int nDec = 0;
    #pragma unroll
    for (int s = 0; s < 4; ++s) {
      int i = tid + (s << 10);
      int wi = i >> 6;
      u64 bit = 1ull << (i & 63);
      if (!(decided[wi] & bit)) {
        bool hasU = false, hasK = false;
        u64 t = mynbrw[s];
        while (t) {
          int w = __builtin_ctzll(t);
          t &= t - 1;
          u64 below = (w < wi) ? ~0ull : (bit - 1ull);
          u64 m = mask[(u64)i * NW + w] & below;
          u64 d = decided[w];
          u64 kp = kept[w];
          hasU = hasU || ((m & ~d) != 0ull);
          hasK = hasK || ((m & kp) != 0ull);
        }
        if (!hasU) { decIdx[nDec] = i; decKept[nDec] = !hasK; ++nDec; }
      }
    }
    __syncthreads();
    for (int d = 0; d < nDec; ++d) {
      int i = decIdx[d];
      u64 bit = 1ull << (i & 63);
      atomicOr(&decided[i >> 6], bit);
      if (decKept[d]) atomicOr(&kept[i >> 6], bit);
      atomicSub(&remaining, 1);
    }
    __syncthreads();
  }
  if (tid < 64) keptOut[tid] = kept[tid];
}

// ---------- K4: supstep[j] = min{i kept : over(i,j)} (parallel), -1 if invalid.
__global__ void __launch_bounds__(256) k_supstep(const u64* __restrict__ mask,
                                                 const u64* __restrict__ kept,
                                                 const float* __restrict__ scoress,
                                                 int* __restrict__ supstep) {
  __shared__ u64 K[64];
  if (threadIdx.x < 64) K[threadIdx.x] = kept[threadIdx.x];
  __syncthreads();
  int j = blockIdx.x * 256 + threadIdx.x;
  if (!(scoress[j] > COND_THRES)) { supstep[j] = -1; return; }
  int res = 0x7FFFFFFF;
  #pragma unroll 4
  for (int w = 0; w < 64; ++w) {
    u64 m = mask[(u64)j * NW + w] & K[w];
    if (m) { res = (w << 6) + __builtin_ctzll(m); break; }
  }
  supstep[j] = res;
}

// ---------- K5: per-box merge + all outputs. One 64-thread block per sorted box.
__global__ void __launch_bounds__(64) k_merge(
    const u64* __restrict__ mask, const int* __restrict__ supstep,
    const float* __restrict__ box9s, const float* __restrict__ scoress,
    const int* __restrict__ labelss,
    const float* __restrict__ w1, const float* __restrict__ b1,
    const float* __restrict__ w2, const float* __restrict__ b2,
    const float* __restrict__ w3, const float* __restrict__ b3,
    float* __restrict__ out) {
  #pragma clang fp contract(off)
  __shared__ int candList[MM];
  __shared__ float ob[MM][7];
  __shared__ float h1[7][HH];
  __shared__ float h2[7][HH];
  __shared__ float res[7];
  int i = blockIdx.x;
  int t = threadIdx.x;
  bool active = (supstep[i] == i);
  u64 wq = 0;
  int cnt = 0;
  if (active) {
    u64 w = mask[(u64)i * NW + t];
    while (w) {
      int b = __builtin_ctzll(w);
      w &= w - 1;
      int j = (t << 6) | b;
      if (supstep[j] >= i) { wq |= (1ull << b); cnt++; }
    }
  }
  int incl = cnt;
  #pragma unroll
  for (int off = 1; off < 64; off <<= 1) {
    int v = __shfl_up(incl, off);
    if (t >= off) incl += v;
  }
  int excl = incl - cnt;
  int count = __shfl(incl, 63);
  bool merged = active && (count > 1);
  if (merged && wq) {
    int pos = excl;
    u64 ww = wq;
    while (ww && pos < MM) {
      int b = __builtin_ctzll(ww);
      ww &= ww - 1;
      candList[pos++] = (t << 6) | b;
    }
  }
  __syncthreads();
  if (merged) {
    int nc = count < MM ? count : MM;
    if (t < MM) {
      if (t < nc) {
        int j = candList[t];
        #pragma unroll
        for (int f = 0; f < 7; ++f) ob[t][f] = box9s[j * 9 + f];
      } else {
        #pragma unroll
        for (int f = 0; f < 7; ++f) ob[t][f] = 0.0f;
      }
    }
    __syncthreads();
    for (int o = t; o < 7 * HH; o += 64) {
      int f = o >> 4, hh = o & 15;
      float acc = b1[hh];
      #pragma unroll
      for (int m = 0; m < MM; ++m) acc += ob[m][f] * w1[m * HH + hh];
      h1[f][hh] = fmaxf(acc, 0.0f);
    }
    __syncthreads();
    for (int o = t; o < 7 * HH; o += 64) {
      int f = o >> 4, oo = o & 15;
      float acc = b2[oo];
      #pragma unroll
      for (int k = 0; k < HH; ++k) acc += h1[f][k] * w2[k * HH + oo];
      h2[f][oo] = fmaxf(acc, 0.0f);
    }
    __syncthreads();
    if (t < 7) {
      float acc = b3[0];
      #pragma unroll
      for (int k = 0; k < HH; ++k) acc += h2[t][k] * w3[k];
      if (t >= 3 && t < 6) acc = fmaxf(acc, 1e-5f);
      res[t] = acc;
    }
    __syncthreads();
  }
  if (t < 9) {
    float v = box9s[i * 9 + t];
    if (merged && t < 7) v = res[t];
    out[i * 9 + t] = v;
  }
  if (t == 0) {
    out[NB * 9 + i]          = scoress[i];
    out[NB * 9 + NB + i]     = (float)labelss[i];
    out[NB * 9 + 2 * NB + i] = active ? 1.0f : 0.0f;
  }
}

extern "C" void kernel_launch(void* const* d_in, const int* in_sizes, int n_in,
                              void* d_out, int out_size, void* d_ws, size_t ws_size,
                              hipStream_t stream) {
  const float* boxes9 = (const float*)d_in[0];
  const float* scores = (const float*)d_in[1];
  const int*   labels = (const int*)d_in[2];
  const float* w1 = (const float*)d_in[3];
  const float* b1 = (const float*)d_in[4];
  const float* w2 = (const float*)d_in[5];
  const float* b2 = (const float*)d_in[6];
  const float* w3 = (const float*)d_in[7];
  const float* b3 = (const float*)d_in[8];
  char* ws = (char*)d_ws;
  u64*    kept    = (u64*)(ws + WS_KEPT);
  u64*    mask    = (u64*)(ws + WS_MASK);
  float*  box9s   = (float*)(ws + WS_BOX9S);
  float4* bevs    = (float4*)(ws + WS_BEVS);
  float*  scoress = (float*)(ws + WS_SCORES);
  int*    labelss = (int*)(ws + WS_LABELS);
  int*    supstep = (int*)(ws + WS_SUPSTEP);
  u64*    nbrw    = (u64*)(ws + WS_NBRW);
  u32*    rank    = (u32*)(ws + WS_RANK);
  float*  out     = (float*)d_out;

  hipMemsetAsync(rank, 0, NB * sizeof(u32), stream);
  hipLaunchKernelGGL(k_rank,    dim3(NB / 256, NB / RJT), dim3(256), 0, stream, scores, rank);
  hipLaunchKernelGGL(k_scatter, dim3(NB / 256), dim3(256), 0, stream, rank, scores, boxes9, labels,
                     box9s, bevs, scoress, labelss);
  hipLaunchKernelGGL(k_mask,    dim3(64, 64),   dim3(64),   0, stream, bevs, labelss, mask);
  hipLaunchKernelGGL(k_nbrw,    dim3(NB / 256), dim3(256),  0, stream, mask, scoress, nbrw);
  hipLaunchKernelGGL(k_nms,     dim3(1),        dim3(1024), 0, stream, mask, nbrw, scoress, kept);
  hipLaunchKernelGGL(k_supstep, dim3(NB / 256), dim3(256),  0, stream, mask, kept, scoress, supstep);
  hipLaunchKernelGGL(k_merge,   dim3(NB),       dim3(64),   0, stream, mask, supstep,
                     box9s, scoress, labelss, w1, b1, w2, b2, w3, b3, out);
}